// Round 3
// baseline (196.421 us; speedup 1.0000x reference)
//
#include <hip/hip_runtime.h>
#include <hip/hip_bf16.h>

// MRConv: B=4, C=192, N=10000, K=16, OUT=384
// out[b,o,n] = relu( sum_ch W[o,ch]*feat[b,ch,n] + bias[o] )
// feat[b,2c,n] = x[b,c,n]; feat[b,2c+1,n] = max_k( x[b,c,e0[b,n,k]] - x[b,c,e1[b,n,k]] )
//
// Round 3: two kernels.
//  k_prep  = transpose x -> xT bf16 [b][n][c] (+ W -> bf16 folded in)
//  k_fused = gather+max straight into LDS (swizzled granules) + 384x64 MFMA GEMM
//            featT HBM round-trip eliminated (~64 MB saved).

#define NB   4
#define NC   192
#define NN   10000
#define NK   16
#define NOUT 384
#define K2C  384            // 2*C

typedef short bf16x8 __attribute__((ext_vector_type(8)));  // 8 bf16 = 4 VGPRs
typedef float f32x4  __attribute__((ext_vector_type(4)));

__device__ inline unsigned short f2bf(float f) {
    unsigned int u = __builtin_bit_cast(unsigned int, f);
    u += ((u >> 16) & 1u) + 0x7FFFu;
    return (unsigned short)(u >> 16);
}
__device__ inline float bflo(unsigned int u) { return __builtin_bit_cast(float, u << 16); }
__device__ inline float bfhi(unsigned int u) { return __builtin_bit_cast(float, u & 0xFFFF0000u); }

// ---------------- K1: transpose x[b][c][n] f32 -> xT[b][n][c] bf16, + W -> bf16 ----------------
// grid 4*157 = 628 blocks, 256 thr. First 576 blocks also convert 256 W elems each.
__global__ __launch_bounds__(256) void k_prep(const float* __restrict__ x,
                                              const float* __restrict__ w,
                                              unsigned short* __restrict__ xT,
                                              unsigned short* __restrict__ wbf) {
    __shared__ unsigned short tile[NC * 65];   // 192 x 64 (+1 pad)
    int gid = blockIdx.x * 256 + threadIdx.x;
    if (gid < NOUT * K2C) wbf[gid] = f2bf(w[gid]);     // 147456 elems, 576 blocks

    int b  = blockIdx.x & 3;
    int nb = (blockIdx.x >> 2) * 64;
    int t  = threadIdx.x;
    const float* xb = x + (size_t)b * NC * NN;
    for (int i = 0; i < 48; ++i) {             // 192*64/256 = 48
        int idx = i * 256 + t;
        int c  = idx >> 6;
        int nl = idx & 63;
        int n  = nb + nl;
        float v = (n < NN) ? xb[(size_t)c * NN + n] : 0.f;   // coalesced along n
        tile[c * 65 + nl] = f2bf(v);
    }
    __syncthreads();
    unsigned int* xTd = (unsigned int*)(xT + (size_t)b * NN * NC);  // 96 dwords per node row
    for (int i = 0; i < 24; ++i) {             // 96*64/256 = 24 packed-dword writes
        int idx = i * 256 + t;
        int nl  = idx / 96;
        int cd  = idx - nl * 96;               // dword = channels {2cd, 2cd+1}
        int n   = nb + nl;
        if (n < NN) {
            unsigned int lo = tile[(2 * cd)     * 65 + nl];
            unsigned int hi = tile[(2 * cd + 1) * 65 + nl];
            xTd[(size_t)n * 96 + cd] = lo | (hi << 16);    // coalesced along cd
        }
    }
}

// ---------------- K2: fused gather+max -> LDS -> MFMA GEMM ----------------
// Block = 64 nodes x 384 outs. 4 waves.
// Phase 1 (gather): wave owns 16 nodes; lanes 0..23 each load one uint4 (8 ch)
//   per gathered row (row = 24 x dwordx4 = 384 B, full-line utilization).
//   Packs feat granule (16B = 8 interleaved ch) into LDS slot nl*48+(j+3nl)%48
//   (same swizzle the B-frag ds_read_b128 wants; write aliasing 2-way = free).
// Phase 2 (MFMA): wave tile 96x64 = 6x4 frags of 16x16x32; A = W direct from L2.
__global__ __launch_bounds__(256, 3) void k_fused(const unsigned short* __restrict__ wbf,
                                                  const unsigned short* __restrict__ xT,
                                                  const int* __restrict__ eidx,
                                                  const float* __restrict__ bias,
                                                  float* __restrict__ out) {
    __shared__ unsigned short lds[64 * 48 * 8];   // 3072 granules x 16B = 48 KB
    int bid  = blockIdx.x;
    int b    = bid & 3;                            // XCD pinning: each XCD serves 1 batch
    int nt   = bid >> 2;                           // 0..156
    int wv   = threadIdx.x >> 6;
    int lane = threadIdx.x & 63;

    const uint4* xr4 = (const uint4*)(xT + (size_t)b * NN * NC);   // 24 uint4 / node row
    const int* e0 = eidx + (size_t)b * NN * NK;                    // neighbors (x_j)
    const int* e1 = eidx + (size_t)NB * NN * NK + (size_t)b * NN * NK;  // centers (x_i)
    int nbase = nt * 64 + wv * 16;

    // ---- hoist all 2x256 edge indices for the wave's 16 nodes (4 dwords/lane each) ----
    int vj[4], vi[4];
#pragma unroll
    for (int i = 0; i < 4; ++i) {
        int idx = i * 64 + lane;                   // element: node nbase+idx/16, k=idx%16
        int n   = nbase + (idx >> 4);
        vj[i] = (n < NN) ? e0[(size_t)nbase * NK + idx] : 0;
        vi[i] = (n < NN) ? e1[(size_t)nbase * NK + idx] : 0;
    }
    int d = lane;
    bool act = (d < 24);                           // 24 lanes cover a 384 B row

#pragma unroll
    for (int qq = 0; qq < 4; ++qq) {               // compile-time reg select for shfl src
        int vjq = vj[qq], viq = vi[qq];
        for (int it2 = 0; it2 < 4; ++it2) {
            int it = qq * 4 + it2;
            int n  = nbase + it;
            if (n < NN) {                          // wave-uniform
                int nl = wv * 16 + it;
                uint4 cx = make_uint4(0, 0, 0, 0);
                if (act) cx = xr4[(size_t)n * 24 + d];   // center row, ch 8d..8d+7
                float m[8];
#pragma unroll
                for (int c = 0; c < 8; ++c) m[c] = -1e30f;
#pragma unroll
                for (int k = 0; k < 16; ++k) {     // 32 independent uint4 loads in flight
                    int sl  = it2 * 16 + k;        // source lane within vj[qq]
                    int jn  = __shfl(vjq, sl, 64);
                    int in_ = __shfl(viq, sl, 64);
                    uint4 jr = make_uint4(0, 0, 0, 0), ir = make_uint4(0, 0, 0, 0);
                    if (act) { jr = xr4[(size_t)jn * 24 + d]; ir = xr4[(size_t)in_ * 24 + d]; }
                    m[0] = fmaxf(m[0], bflo(jr.x) - bflo(ir.x));
                    m[1] = fmaxf(m[1], bfhi(jr.x) - bfhi(ir.x));
                    m[2] = fmaxf(m[2], bflo(jr.y) - bflo(ir.y));
                    m[3] = fmaxf(m[3], bfhi(jr.y) - bfhi(ir.y));
                    m[4] = fmaxf(m[4], bflo(jr.z) - bflo(ir.z));
                    m[5] = fmaxf(m[5], bfhi(jr.z) - bfhi(ir.z));
                    m[6] = fmaxf(m[6], bflo(jr.w) - bflo(ir.w));
                    m[7] = fmaxf(m[7], bfhi(jr.w) - bfhi(ir.w));
                }
                if (act) {
                    unsigned int mm[4];
#pragma unroll
                    for (int c = 0; c < 4; ++c)
                        mm[c] = (unsigned int)f2bf(m[2 * c]) | ((unsigned int)f2bf(m[2 * c + 1]) << 16);
                    // out dword c = { x_c (lo) | m_c (hi) }; lane covers out dwords 8d..8d+7
                    uint4 g0, g1;
                    g0.x = (cx.x & 0xFFFFu) | (mm[0] << 16);
                    g0.y = (cx.x >> 16)     | (mm[0] & 0xFFFF0000u);
                    g0.z = (cx.y & 0xFFFFu) | (mm[1] << 16);
                    g0.w = (cx.y >> 16)     | (mm[1] & 0xFFFF0000u);
                    g1.x = (cx.z & 0xFFFFu) | (mm[2] << 16);
                    g1.y = (cx.z >> 16)     | (mm[2] & 0xFFFF0000u);
                    g1.z = (cx.w & 0xFFFFu) | (mm[3] << 16);
                    g1.w = (cx.w >> 16)     | (mm[3] & 0xFFFF0000u);
                    int s0 = nl * 48 + (2 * d     + 3 * nl) % 48;   // granule 2d
                    int s1 = nl * 48 + (2 * d + 1 + 3 * nl) % 48;   // granule 2d+1
                    *(uint4*)&lds[(size_t)s0 * 8] = g0;
                    *(uint4*)&lds[(size_t)s1 * 8] = g1;
                }
            }
        }
    }

    // ---- MFMA phase ----
    int r = lane & 15;
    int q = lane >> 4;
    const unsigned short* aptr = wbf + (size_t)(wv * 96 + r) * K2C + q * 8;
    unsigned int nbs[4], u0[4];
#pragma unroll
    for (int ni = 0; ni < 4; ++ni) {
        unsigned int n_ = ni * 16 + r;
        nbs[ni] = n_ * 48u;
        u0[ni]  = ((unsigned int)q + 3u * n_) % 48u;
    }
    f32x4 acc[6][4];
#pragma unroll
    for (int mi = 0; mi < 6; ++mi)
#pragma unroll
        for (int ni = 0; ni < 4; ++ni)
            acc[mi][ni] = (f32x4){0.f, 0.f, 0.f, 0.f};

    __syncthreads();

#pragma unroll 2
    for (int t = 0; t < 12; ++t) {
        bf16x8 a[6], bb[4];
#pragma unroll
        for (int mi = 0; mi < 6; ++mi)
            a[mi] = *(const bf16x8*)(aptr + (size_t)mi * 16 * K2C + t * 32);
#pragma unroll
        for (int ni = 0; ni < 4; ++ni) {
            unsigned int u = u0[ni] + 4u * t;
            if (u >= 48u) u -= 48u;
            bb[ni] = *(const bf16x8*)(lds + (size_t)(nbs[ni] + u) * 8);
        }
#pragma unroll
        for (int mi = 0; mi < 6; ++mi)
#pragma unroll
            for (int ni = 0; ni < 4; ++ni)
                acc[mi][ni] = __builtin_amdgcn_mfma_f32_16x16x32_bf16(a[mi], bb[ni], acc[mi][ni], 0, 0, 0);
    }

    float* ob = out + (size_t)b * NOUT * NN;
#pragma unroll
    for (int mi = 0; mi < 6; ++mi) {
        int obase = wv * 96 + mi * 16 + q * 4;
        float4 b4 = *(const float4*)(bias + obase);   // 16B-aligned
#pragma unroll
        for (int ni = 0; ni < 4; ++ni) {
            int n = nt * 64 + ni * 16 + r;
            if (n < NN) {
                float bv[4] = {b4.x, b4.y, b4.z, b4.w};
#pragma unroll
                for (int rr = 0; rr < 4; ++rr) {
                    float val = acc[mi][ni][rr] + bv[rr];
                    ob[(size_t)(obase + rr) * NN + n] = fmaxf(val, 0.f);
                }
            }
        }
    }
}

extern "C" void kernel_launch(void* const* d_in, const int* in_sizes, int n_in,
                              void* d_out, int out_size, void* d_ws, size_t ws_size,
                              hipStream_t stream) {
    const float* x    = (const float*)d_in[0];   // [4,192,10000,1]
    const int*   eidx = (const int*)d_in[1];     // [2,4,10000,16]
    const float* w    = (const float*)d_in[2];   // [384,384]
    const float* bias = (const float*)d_in[3];   // [384]
    float* out = (float*)d_out;                  // [4,384,10000,1,1]

    // workspace: xT [4][10000][192] bf16 (15.36 MB) | wbf [384][384] bf16 (0.29 MB)
    unsigned short* xT  = (unsigned short*)d_ws;
    unsigned short* wbf = xT + (size_t)NB * NN * NC;

    hipLaunchKernelGGL(k_prep,  dim3(4 * 157), dim3(256), 0, stream, x, w, xT, wbf);
    hipLaunchKernelGGL(k_fused, dim3(4 * 157), dim3(256), 0, stream, wbf, xT, eidx, bias, out);
}

// Round 4
// 195.213 us; speedup vs baseline: 1.0062x; 1.0062x over previous
//
#include <hip/hip_runtime.h>

// MRConv: B=4, C=192, N=10000, K=16, OUT=384
// out[b,o,n] = relu( sum_ch W[o,ch]*feat[b,ch,n] + bias[o] )
// feat[b,2c,n] = x[b,c,n]; feat[b,2c+1,n] = max_k( x[b,c,e0[b,n,k]] - x[b,c,e1[b,n,k]] )
//
// Round 4: f16 pipeline (packed v_pk_add/max_f16 gather + mfma f16), 32-node
// fused tiles, LDS row stride padded to 49 granules (conflict-free b128 R+W),
// readlane/SGPR edge indices.

#define NB   4
#define NC   192
#define NN   10000
#define NK   16
#define NOUT 384
#define K2C  384            // 2*C

typedef _Float16 f16x8 __attribute__((ext_vector_type(8)));  // 4 VGPRs (MFMA A/B)
typedef _Float16 h2    __attribute__((ext_vector_type(2)));  // packed pair
typedef float    f32x4 __attribute__((ext_vector_type(4)));

__device__ inline unsigned short f2h(float f) {
    _Float16 h = (_Float16)f;
    return __builtin_bit_cast(unsigned short, h);
}

// ---------------- K1: transpose x[b][c][n] f32 -> xT[b][n][c] f16, + W -> f16 ----------------
// grid 4*157 = 628 blocks, 256 thr. First 576 blocks also convert 256 W elems each.
__global__ __launch_bounds__(256) void k_prep(const float* __restrict__ x,
                                              const float* __restrict__ w,
                                              unsigned short* __restrict__ xT,
                                              unsigned short* __restrict__ wh) {
    __shared__ unsigned short tile[NC * 65];   // 192 x 64 (+1 pad)
    int gid = blockIdx.x * 256 + threadIdx.x;
    if (gid < NOUT * K2C) wh[gid] = f2h(w[gid]);       // 147456 elems

    int b  = blockIdx.x & 3;
    int nb = (blockIdx.x >> 2) * 64;
    int t  = threadIdx.x;
    const float* xb = x + (size_t)b * NC * NN;
    for (int i = 0; i < 48; ++i) {             // 192*64/256
        int idx = i * 256 + t;
        int c  = idx >> 6;
        int nl = idx & 63;
        int n  = nb + nl;
        float v = (n < NN) ? xb[(size_t)c * NN + n] : 0.f;   // coalesced along n
        tile[c * 65 + nl] = f2h(v);
    }
    __syncthreads();
    unsigned int* xTd = (unsigned int*)(xT + (size_t)b * NN * NC);  // 96 dwords / node row
    for (int i = 0; i < 24; ++i) {             // 96*64/256 packed-dword writes
        int idx = i * 256 + t;
        int nl  = idx / 96;
        int cd  = idx - nl * 96;               // dword = channels {2cd, 2cd+1}
        int n   = nb + nl;
        if (n < NN) {
            unsigned int lo = tile[(2 * cd)     * 65 + nl];
            unsigned int hi = tile[(2 * cd + 1) * 65 + nl];
            xTd[(size_t)n * 96 + cd] = lo | (hi << 16);    // coalesced along cd
        }
    }
}

// ---------------- K2: fused gather+max -> LDS -> MFMA GEMM ----------------
// Block = 32 nodes x 384 outs, 4 waves. grid 4*313 = 1252 (~4.9 blocks/CU).
// LDS: 32 rows x 49 granules x 16B = 25088 B (stride 49 = +4 dwords mod 32 per
// row -> conflict-free b128 reads across rows; writes are consecutive granules
// within one row -> conflict-free).
// Phase 1: wave owns 8 nodes. Edge indices -> SGPR via readlane; lanes 0..47
//   each load uint2 (4 ch) per 384B row; packed f16 sub+max (v_pk_*); lanes
//   48..63 clamp to granule 47 (same data, benign same-value LDS write).
// Phase 2: wave tile 96 out x 32 n = 6x2 frags of mfma_f32_16x16x32_f16;
//   A = W f16 direct from L2 (same lines for all blocks).
__global__ __launch_bounds__(256, 4) void k_fused(const unsigned short* __restrict__ wh,
                                                  const unsigned short* __restrict__ xT,
                                                  const int* __restrict__ eidx,
                                                  const float* __restrict__ bias,
                                                  float* __restrict__ out) {
    __shared__ unsigned short lds[32 * 49 * 8];   // 25088 B
    int bid  = blockIdx.x;
    int b    = bid & 3;                            // XCD pinning: batch b -> XCDs {b, b+4}
    int nt   = bid >> 2;                           // 0..312
    int wv   = threadIdx.x >> 6;
    int lane = threadIdx.x & 63;

    const uint2* xr2 = (const uint2*)(xT + (size_t)b * NN * NC);   // 48 uint2 / node row
    const int* e0 = eidx + (size_t)b * NN * NK;                    // neighbors (x_j)
    const int* e1 = eidx + (size_t)NB * NN * NK + (size_t)b * NN * NK;  // centers (x_i)
    int nbase = nt * 32 + wv * 8;

    // ---- edge indices for the wave's 8 nodes: element i*64+lane = (node idx/16, k=idx%16) ----
    int ej[2], ei[2];
#pragma unroll
    for (int i = 0; i < 2; ++i) {
        int idx = i * 64 + lane;
        int nn  = nbase + (idx >> 4);
        ej[i] = (nn < NN) ? e0[(size_t)nbase * NK + idx] : 0;
        ei[i] = (nn < NN) ? e1[(size_t)nbase * NK + idx] : 0;
    }
    int dc = (lane < 48) ? lane : 47;              // clamped granule id (no divergence)

#pragma unroll 1
    for (int it = 0; it < 8; ++it) {               // one node per iteration
        int n = nbase + it;
        if (n < NN) {                              // wave-uniform
            int nl = wv * 8 + it;
            uint2 cx = xr2[(size_t)n * 48 + dc];   // center row, ch 4dc..4dc+3
            h2 m0 = __builtin_bit_cast(h2, 0xFC00FC00u);   // (-inf, -inf)
            h2 m1 = m0;
#pragma unroll
            for (int k = 0; k < 16; ++k) {
                int j  = __builtin_amdgcn_readlane(ej[it >> 2], ((it & 3) * 16) + k);
                int i_ = __builtin_amdgcn_readlane(ei[it >> 2], ((it & 3) * 16) + k);
                uint2 jr = xr2[(size_t)j  * 48 + dc];      // saddr + fixed voffset
                uint2 ir = xr2[(size_t)i_ * 48 + dc];
                h2 dlo = __builtin_bit_cast(h2, jr.x) - __builtin_bit_cast(h2, ir.x);
                h2 dhi = __builtin_bit_cast(h2, jr.y) - __builtin_bit_cast(h2, ir.y);
                m0 = __builtin_elementwise_max(m0, dlo);   // v_pk_max_f16
                m1 = __builtin_elementwise_max(m1, dhi);
            }
            unsigned int mb0 = __builtin_bit_cast(unsigned int, m0);
            unsigned int mb1 = __builtin_bit_cast(unsigned int, m1);
            // granule = interleaved (x_c, m_c) for ch 4dc..4dc+3
            uint4 g;
            g.x = (cx.x & 0xFFFFu) | (mb0 << 16);
            g.y = (cx.x >> 16)     | (mb0 & 0xFFFF0000u);
            g.z = (cx.y & 0xFFFFu) | (mb1 << 16);
            g.w = (cx.y >> 16)     | (mb1 & 0xFFFF0000u);
            *(uint4*)&lds[(size_t)(nl * 49 + dc) * 8] = g; // consecutive granules: no conflict
        }
    }

    // ---- MFMA phase: 6x2 frags of 16x16x32 f16 ----
    int r = lane & 15;
    int q = lane >> 4;
    const unsigned short* aptr = wh + (size_t)(wv * 96 + r) * K2C + q * 8;
    f32x4 acc[6][2];
#pragma unroll
    for (int mi = 0; mi < 6; ++mi)
#pragma unroll
        for (int ni = 0; ni < 2; ++ni)
            acc[mi][ni] = (f32x4){0.f, 0.f, 0.f, 0.f};

    __syncthreads();

#pragma unroll 2
    for (int t = 0; t < 12; ++t) {
        f16x8 a[6], bb[2];
#pragma unroll
        for (int mi = 0; mi < 6; ++mi)
            a[mi] = *(const f16x8*)(aptr + (size_t)mi * 16 * K2C + t * 32);
#pragma unroll
        for (int ni = 0; ni < 2; ++ni) {
            int row = ni * 16 + r;
            bb[ni] = *(const f16x8*)&lds[(size_t)(row * 49 + 4 * t + q) * 8];
        }
#pragma unroll
        for (int mi = 0; mi < 6; ++mi)
#pragma unroll
            for (int ni = 0; ni < 2; ++ni)
                acc[mi][ni] = __builtin_amdgcn_mfma_f32_16x16x32_f16(a[mi], bb[ni], acc[mi][ni], 0, 0, 0);
    }

    float* ob = out + (size_t)b * NOUT * NN;
#pragma unroll
    for (int mi = 0; mi < 6; ++mi) {
        int obase = wv * 96 + mi * 16 + q * 4;
        float4 b4 = *(const float4*)(bias + obase);   // 16B-aligned
        float bv[4] = {b4.x, b4.y, b4.z, b4.w};
#pragma unroll
        for (int ni = 0; ni < 2; ++ni) {
            int n = nt * 32 + ni * 16 + r;
            if (n < NN) {
#pragma unroll
                for (int rr = 0; rr < 4; ++rr) {
                    float val = acc[mi][ni][rr] + bv[rr];
                    ob[(size_t)(obase + rr) * NN + n] = fmaxf(val, 0.f);
                }
            }
        }
    }
}

extern "C" void kernel_launch(void* const* d_in, const int* in_sizes, int n_in,
                              void* d_out, int out_size, void* d_ws, size_t ws_size,
                              hipStream_t stream) {
    const float* x    = (const float*)d_in[0];   // [4,192,10000,1]
    const int*   eidx = (const int*)d_in[1];     // [2,4,10000,16]
    const float* w    = (const float*)d_in[2];   // [384,384]
    const float* bias = (const float*)d_in[3];   // [384]
    float* out = (float*)d_out;                  // [4,384,10000,1,1]

    // workspace: xT [4][10000][192] f16 (15.36 MB) | wh [384][384] f16 (0.29 MB)
    unsigned short* xT = (unsigned short*)d_ws;
    unsigned short* wh = xT + (size_t)NB * NN * NC;

    hipLaunchKernelGGL(k_prep,  dim3(4 * 157), dim3(256), 0, stream, x, w, xT, wh);
    hipLaunchKernelGGL(k_fused, dim3(4 * 313), dim3(256), 0, stream, wh, xT, eidx, bias, out);
}